// Round 1
// baseline (166.168 us; speedup 1.0000x reference)
//
#include <hip/hip_runtime.h>

#define EPS 1e-6f

__device__ __forceinline__ float sel8(const float v[8], int k) {
    // constant-index accesses only -> stays in registers (cndmask chain)
    float r = v[0];
#pragma unroll
    for (int i = 1; i < 8; ++i) r = (k == i) ? v[i] : r;
    return r;
}

__device__ __forceinline__ float norm2f(float dx, float dy) {
    return sqrtf(dx * dx + dy * dy);
}

__global__ __launch_bounds__(256) void gsc_loss_kernel(
    const float* __restrict__ pred, const float* __restrict__ gt,
    float* __restrict__ acc, int B)
{
    int b = blockIdx.x * blockDim.x + threadIdx.x;
    float L = 0.0f;
    float vflag = 0.0f;

    if (b < B) {
        // 24 floats (8 kpts x 3) per row per tensor; row base = 96 B (16B aligned)
        const float4* p4 = reinterpret_cast<const float4*>(pred) + (size_t)b * 6;
        const float4* g4 = reinterpret_cast<const float4*>(gt)   + (size_t)b * 6;
        float pb[24], gb[24];
#pragma unroll
        for (int i = 0; i < 6; ++i) {
            float4 pv = p4[i];
            float4 gv = g4[i];
            pb[4 * i + 0] = pv.x; pb[4 * i + 1] = pv.y;
            pb[4 * i + 2] = pv.z; pb[4 * i + 3] = pv.w;
            gb[4 * i + 0] = gv.x; gb[4 * i + 1] = gv.y;
            gb[4 * i + 2] = gv.z; gb[4 * i + 3] = gv.w;
        }

        // visibility mask + count
        unsigned mask = 0;
        int vcnt = 0;
#pragma unroll
        for (int k = 0; k < 8; ++k) {
            bool vis = (pb[3 * k + 2] > 0.5f) && (gb[3 * k + 2] > 0.5f);
            if (vis) { mask |= (1u << k); ++vcnt; }
        }

        // rows with <4 visible are invalid -> contribute 0; skip entirely.
        if (vcnt >= 4) {
            vflag = 1.0f;

            float px8[8], py8[8], gx8[8], gy8[8];
#pragma unroll
            for (int k = 0; k < 8; ++k) {
                px8[k] = pb[3 * k + 0]; py8[k] = pb[3 * k + 1];
                gx8[k] = gb[3 * k + 0]; gy8[k] = gb[3 * k + 1];
            }

            // first 4 visible indices (stable order = ascending bit positions)
            float px[4], py[4], gx[4], gy[4];
            unsigned m = mask;
#pragma unroll
            for (int i = 0; i < 4; ++i) {
                int k = __ffs(m) - 1;
                m &= m - 1;
                px[i] = sel8(px8, k); py[i] = sel8(py8, k);
                gx[i] = sel8(gx8, k); gy[i] = sel8(gy8, k);
            }

            // ---- L_shape: cross-ratio of diagonals ----
            float pd31x = px[2] - px[0], pd31y = py[2] - py[0];
            float pd42x = px[3] - px[1], pd42y = py[3] - py[1];
            float gd31x = gx[2] - gx[0], gd31y = gy[2] - gy[0];
            float gd42x = gx[3] - gx[1], gd42y = gy[3] - gy[1];
            float pred_cr = norm2f(pd31x, pd31y) / (norm2f(pd42x, pd42y) + EPS);
            float gt_cr   = norm2f(gd31x, gd31y) / (norm2f(gd42x, gd42y) + EPS);
            float L_shape = fabsf(pred_cr - gt_cr);

            // ---- L_edge: edge-length parity + corner orthogonality ----
            float v12x = px[1] - px[0], v12y = py[1] - py[0];
            float v23x = px[2] - px[1], v23y = py[2] - py[1];
            float v34x = px[3] - px[2], v34y = py[3] - py[2];
            float v41x = px[0] - px[3], v41y = py[0] - py[3];
            float l12 = norm2f(v12x, v12y), l23 = norm2f(v23x, v23y);
            float l34 = norm2f(v34x, v34y), l41 = norm2f(v41x, v41y);
            float par1 = fabsf(l12 - l34) / (l12 + l34 + EPS);
            float par2 = fabsf(l23 - l41) / (l23 + l41 + EPS);
            float dot1 = fabsf((v12x * v41x + v12y * v41y) / (l12 * l41 + EPS));
            float dot2 = fabsf((v12x * v23x + v12y * v23y) / (l12 * l23 + EPS));
            float dot3 = fabsf((v23x * v34x + v23y * v34y) / (l23 * l34 + EPS));
            float dot4 = fabsf((v34x * v41x + v34y * v41y) / (l34 * l41 + EPS));
            float L_edge = 0.5f * (par1 + par2) + 0.25f * (dot1 + dot2 + dot3 + dot4);

            // ---- L_pos ----
            float dist = 0.25f * (norm2f(px[0] - gx[0], py[0] - gy[0]) +
                                  norm2f(px[1] - gx[1], py[1] - gy[1]) +
                                  norm2f(px[2] - gx[2], py[2] - gy[2]) +
                                  norm2f(px[3] - gx[3], py[3] - gy[3]));

            float p21x = px[1] - px[0], p21y = py[1] - py[0];
            float p41x = px[3] - px[0], p41y = py[3] - py[0];
            float g21x = gx[1] - gx[0], g21y = gy[1] - gy[0];
            float g41x = gx[3] - gx[0], g41y = gy[3] - gy[0];
            float pred_area = 0.5f * fabsf(p21x * pd31y - p21y * pd31x)
                            + 0.5f * fabsf(pd31x * p41y - pd31y * p41x);
            float gt_area   = 0.5f * fabsf(g21x * gd31y - g21y * gd31x)
                            + 0.5f * fabsf(gd31x * g41y - gd31y * g41x);
            float area_ratio = fabsf(pred_area - gt_area) / (gt_area + EPS);

            float mpx = 0.25f * (px[0] + px[1] + px[2] + px[3]);
            float mpy = 0.25f * (py[0] + py[1] + py[2] + py[3]);
            float mgx = 0.25f * (gx[0] + gx[1] + gx[2] + gx[3]);
            float mgy = 0.25f * (gy[0] + gy[1] + gy[2] + gy[3]);
            float rel_cons = 0.0f;
#pragma unroll
            for (int i = 0; i < 4; ++i) {
                rel_cons += norm2f((px[i] - mpx) - (gx[i] - mgx),
                                   (py[i] - mpy) - (gy[i] - mgy));
            }
            rel_cons *= 0.25f;

            float L_pos = 0.4f * dist + 0.3f * area_ratio + 0.3f * rel_cons;
            L = 0.4f * L_shape + 0.3f * L_edge + 0.3f * L_pos;
        }
    }

    // ---- reduction: wave64 shuffle -> LDS -> one atomic per block ----
#pragma unroll
    for (int off = 32; off > 0; off >>= 1) {
        L     += __shfl_down(L, off, 64);
        vflag += __shfl_down(vflag, off, 64);
    }
    __shared__ float sL[4], sV[4];
    int lane = threadIdx.x & 63;
    int wv   = threadIdx.x >> 6;
    if (lane == 0) { sL[wv] = L; sV[wv] = vflag; }
    __syncthreads();
    if (threadIdx.x == 0) {
        float tL = sL[0] + sL[1] + sL[2] + sL[3];
        float tV = sV[0] + sV[1] + sV[2] + sV[3];
        atomicAdd(&acc[0], tL);
        atomicAdd(&acc[1], tV);
    }
}

__global__ void gsc_finalize_kernel(const float* __restrict__ acc,
                                    float* __restrict__ out)
{
    float total = acc[0];
    float n     = acc[1];
    out[0] = (n > 0.0f) ? (total / n) : 0.0f;
}

extern "C" void kernel_launch(void* const* d_in, const int* in_sizes, int n_in,
                              void* d_out, int out_size, void* d_ws, size_t ws_size,
                              hipStream_t stream) {
    const float* pred = (const float*)d_in[0];
    const float* gt   = (const float*)d_in[1];
    float* out = (float*)d_out;
    float* acc = (float*)d_ws;   // [0]=sum(L), [1]=n_valid

    int B = in_sizes[0] / 24;    // 524288

    hipMemsetAsync(acc, 0, 2 * sizeof(float), stream);

    int block = 256;
    int grid = (B + block - 1) / block;
    gsc_loss_kernel<<<grid, block, 0, stream>>>(pred, gt, acc, B);
    gsc_finalize_kernel<<<1, 1, 0, stream>>>(acc, out);
}